// Round 5
// baseline (2999.441 us; speedup 1.0000x reference)
//
#include <hip/hip_runtime.h>
#include <hip/hip_fp16.h>

#define B_    128
#define T_    1024
#define NTH   256
#define NREG  112           // f16 pairs per row in VGPRs (cols 0..223)
#define NQR   28            // NREG/4 h-quads for register part
#define NQL   4             // LDS quads per row (cols 224..255)

typedef _Float16 half2_t __attribute__((ext_vector_type(2)));

__device__ __forceinline__ float fdot2(unsigned int w, unsigned int h, float acc) {
    return __builtin_amdgcn_fdot2(__builtin_bit_cast(half2_t, w),
                                  __builtin_bit_cast(half2_t, h), acc, false);
}
__device__ __forceinline__ unsigned int packf16(float a, float b) {
    half2_t h;
    h.x = (_Float16)a;
    h.y = (_Float16)b;
    return __builtin_bit_cast(unsigned int, h);
}

// ---------------------------------------------------------------------------
// Kernel 1: persistent LSTM. 1 block/batch, 256 threads; thread u owns ALL
// FOUR gate rows of unit u (i:u, f:256+u, g:512+u, o:768+u) -> activation is
// thread-local, no gate exchange, 1 barrier/step (double-buffered h).
// 112 pairs/row x 4 rows = 448 weight VGPRs (1 wave/SIMD -> 512 budget via
// amdgpu_waves_per_eu(1,1)). Cols 224..255 (4 quads/row) in LDS.
// ---------------------------------------------------------------------------
__global__ __attribute__((amdgpu_flat_work_group_size(NTH, NTH),
                          amdgpu_waves_per_eu(1, 1)))
void lstm_k(const float* __restrict__ x, const float* __restrict__ w_ih,
            const float* __restrict__ w_hh, const float* __restrict__ b_ih,
            const float* __restrict__ b_hh, unsigned int* __restrict__ hT_p) {
    extern __shared__ unsigned char smem[];
    uint4*        w_lds4 = (uint4*)smem;                      // [16][256] quads = 64 KB
    unsigned int* hbuf   = (unsigned int*)(smem + 65536);     // [2][128] packed f16 pairs
    float*        xseq   = (float*)(smem + 65536 + 1024);     // [1024]

    const int u = threadIdx.x;
    const int b = blockIdx.x;

    float bs[4], wi[4];
#pragma unroll
    for (int g = 0; g < 4; ++g) {
        const int r = g * 256 + u;
        bs[g] = b_ih[r] + b_hh[r];
        wi[g] = w_ih[r];
    }

    // xseq[t] = x[b, (t%512)*2 + t/512]
    for (int t = u; t < T_; t += NTH)
        xseq[t] = x[b * T_ + ((t & 511) << 1) + (t >> 9)];

    // register weights: cols [0, 224) of each of this thread's 4 rows
    unsigned int wr[4][NREG];
#pragma unroll
    for (int g = 0; g < 4; ++g) {
        const float* row = &w_hh[(size_t)(g * 256 + u) * 256];
#pragma unroll
        for (int p = 0; p < NREG; p += 2) {
            float4 a4 = *(const float4*)&row[2 * p];
            wr[g][p]     = packf16(a4.x, a4.y);
            wr[g][p + 1] = packf16(a4.z, a4.w);
        }
    }
    // LDS weights: cols [224, 256) -> quad (g,q,u); reads lane-consecutive
#pragma unroll
    for (int g = 0; g < 4; ++g) {
#pragma unroll
        for (int q = 0; q < NQL; ++q) {
            const float* src = &w_hh[(size_t)(g * 256 + u) * 256 + 2 * NREG + 8 * q];
            float4 a4 = ((const float4*)src)[0];
            float4 c4 = ((const float4*)src)[1];
            uint4 pk;
            pk.x = packf16(a4.x, a4.y); pk.y = packf16(a4.z, a4.w);
            pk.z = packf16(c4.x, c4.y); pk.w = packf16(c4.z, c4.w);
            w_lds4[(g * NQL + q) * 256 + u] = pk;
        }
    }
    if (u < 128) { hbuf[u] = 0u; hbuf[128 + u] = 0u; }
    float c_state = 0.f;
    __syncthreads();

    for (int t = 0; t < T_; ++t) {
        const uint4* h4 = (const uint4*)&hbuf[(t & 1) * 128];
        const float  xt = xseq[t];
        float a0[4], a1[4];
#pragma unroll
        for (int g = 0; g < 4; ++g) {
            a0[g] = fmaf(xt, wi[g], bs[g]);
            a1[g] = 0.f;
        }
#pragma unroll
        for (int q = 0; q < NQR; ++q) {
            uint4 hp = h4[q];                       // broadcast b128
#pragma unroll
            for (int g = 0; g < 4; ++g) {
                a0[g] = fdot2(wr[g][4 * q + 0], hp.x, a0[g]);
                a1[g] = fdot2(wr[g][4 * q + 1], hp.y, a1[g]);
                a0[g] = fdot2(wr[g][4 * q + 2], hp.z, a0[g]);
                a1[g] = fdot2(wr[g][4 * q + 3], hp.w, a1[g]);
            }
        }
#pragma unroll
        for (int q = 0; q < NQL; ++q) {
            uint4 hp = h4[NQR + q];
#pragma unroll
            for (int g = 0; g < 4; ++g) {
                uint4 w = w_lds4[(g * NQL + q) * 256 + u];
                a0[g] = fdot2(w.x, hp.x, a0[g]);
                a1[g] = fdot2(w.y, hp.y, a1[g]);
                a0[g] = fdot2(w.z, hp.z, a0[g]);
                a1[g] = fdot2(w.w, hp.w, a1[g]);
            }
        }
        const float gi = a0[0] + a1[0], gf = a0[1] + a1[1];
        const float gg = a0[2] + a1[2], go = a0[3] + a1[3];
        const float i_ = __builtin_amdgcn_rcpf(1.f + __expf(-gi));
        const float f_ = __builtin_amdgcn_rcpf(1.f + __expf(-gf));
        const float g_ = 1.f - 2.f * __builtin_amdgcn_rcpf(__expf(2.f * gg) + 1.f);
        const float o_ = __builtin_amdgcn_rcpf(1.f + __expf(-go));
        c_state = f_ * c_state + i_ * g_;
        const float h = o_ * (1.f - 2.f * __builtin_amdgcn_rcpf(__expf(2.f * c_state) + 1.f));
        ((__half*)&hbuf[((t + 1) & 1) * 128])[u] = __float2half(h);
        __syncthreads();
        if (t >= 512 && u < 128)
            hT_p[(size_t)(((t - 512) << 7) + u) * B_ + b] = hbuf[((t + 1) & 1) * 128 + u];
    }
}

// ---------------------------------------------------------------------------
// Kernel 2: res1 partials, LDS-staged. Grid (16 m-tiles, 32 k-splits),
// 256 threads. w1 packed f16 in LDS; reads wave-uniform b128 broadcasts.
// h reads coalesced. part[(ks*256+m)*128+b].
// ---------------------------------------------------------------------------
#define WST 260
__global__ __launch_bounds__(256, 2) void gemm1_k(
    const unsigned int* __restrict__ hT_p, const float* __restrict__ w1,
    float* __restrict__ part) {
    __shared__ unsigned int w_stage[16 * WST];   // 16.6 KB

    const int tid = threadIdx.x;
    const int m0  = blockIdx.x * 16;
    const int ks  = blockIdx.y;                  // 0..31
    const int bl  = tid & 127;
    const int mg  = tid >> 7;                    // wave-uniform
    const int srow = tid >> 4, slane = tid & 15;

    float acc[8];
#pragma unroll
    for (int j = 0; j < 8; ++j) acc[j] = 0.f;

    const int kbase = ks * 2048;
    for (int s = 0; s < 8; ++s) {
        const int k0 = kbase + s * 256;
        __syncthreads();
        const float* wrow = &w1[(size_t)(m0 + srow) * 131072 + 2 * k0];
#pragma unroll
        for (int i = 0; i < 8; ++i) {
            const int f = slane + 16 * i;
            float4 v = *(const float4*)&wrow[4 * f];
            w_stage[srow * WST + 2 * f]     = packf16(v.x, v.y);
            w_stage[srow * WST + 2 * f + 1] = packf16(v.z, v.w);
        }
        __syncthreads();
#pragma unroll 4
        for (int kg = 0; kg < 64; ++kg) {
            const int kp = 4 * kg;
            unsigned int h0 = hT_p[(size_t)(k0 + kp) * B_ + bl];
            unsigned int h1 = hT_p[(size_t)(k0 + kp + 1) * B_ + bl];
            unsigned int h2 = hT_p[(size_t)(k0 + kp + 2) * B_ + bl];
            unsigned int h3 = hT_p[(size_t)(k0 + kp + 3) * B_ + bl];
#pragma unroll
            for (int j = 0; j < 8; ++j) {
                uint4 w = *(const uint4*)&w_stage[(mg * 8 + j) * WST + kp];
                acc[j] = fdot2(w.x, h0, acc[j]);
                acc[j] = fdot2(w.y, h1, acc[j]);
                acc[j] = fdot2(w.z, h2, acc[j]);
                acc[j] = fdot2(w.w, h3, acc[j]);
            }
        }
    }
#pragma unroll
    for (int j = 0; j < 8; ++j)
        part[(size_t)(ks * 256 + m0 + mg * 8 + j) * B_ + bl] = acc[j];
}

// ---------------------------------------------------------------------------
// Kernel 3: reduce partials over 32 k-splits (+b1, ReLU) -> res1T[m*128+b].
// ---------------------------------------------------------------------------
__global__ __launch_bounds__(128, 8) void reduce_k(
    const float* __restrict__ part, const float* __restrict__ b1,
    float* __restrict__ res1T) {
    const int m = blockIdx.x, bl = threadIdx.x;
    float s = b1[m];
#pragma unroll 8
    for (int kc = 0; kc < 32; ++kc)
        s += part[(size_t)(kc * 256 + m) * B_ + bl];
    res1T[m * B_ + bl] = fmaxf(s, 0.f);
}

// ---------------------------------------------------------------------------
// Kernel 4: res2 = res1@w2.T+b2 ; out = res2@w3.T+b3. 1 block/batch row.
// ---------------------------------------------------------------------------
__global__ __launch_bounds__(512, 2) void head_k(
    const float* __restrict__ res1T, const float* __restrict__ w2,
    const float* __restrict__ b2, const float* __restrict__ w3,
    const float* __restrict__ b3, float* __restrict__ out) {
    __shared__ float r1s[256];
    __shared__ float r2s[512];
    const int tid = threadIdx.x;
    const int b   = blockIdx.x;

    if (tid < 256) r1s[tid] = res1T[tid * B_ + b];
    __syncthreads();
    {
        float s = b2[tid];
        const float* wr = &w2[tid * 256];
#pragma unroll 4
        for (int k = 0; k < 256; k += 4) {
            float4 w = *(const float4*)&wr[k];
            s += r1s[k] * w.x + r1s[k + 1] * w.y + r1s[k + 2] * w.z + r1s[k + 3] * w.w;
        }
        r2s[tid] = s;
    }
    __syncthreads();
    if (tid < 64) {
        float s = b3[tid];
        const float* wr = &w3[tid * 512];
#pragma unroll 4
        for (int k = 0; k < 512; k += 4) {
            float4 w = *(const float4*)&wr[k];
            s += r2s[k] * w.x + r2s[k + 1] * w.y + r2s[k + 2] * w.z + r2s[k + 3] * w.w;
        }
        out[b * 64 + tid] = s;
    }
}

extern "C" void kernel_launch(void* const* d_in, const int* in_sizes, int n_in,
                              void* d_out, int out_size, void* d_ws, size_t ws_size,
                              hipStream_t stream) {
    (void)in_sizes; (void)n_in; (void)out_size; (void)ws_size;
    const float* x    = (const float*)d_in[0];
    const float* w_ih = (const float*)d_in[1];
    const float* w_hh = (const float*)d_in[2];
    const float* b_ih = (const float*)d_in[3];
    const float* b_hh = (const float*)d_in[4];
    const float* w1   = (const float*)d_in[5];
    const float* b1   = (const float*)d_in[6];
    const float* w2   = (const float*)d_in[7];
    const float* b2   = (const float*)d_in[8];
    const float* w3   = (const float*)d_in[9];
    const float* b3   = (const float*)d_in[10];
    float* out = (float*)d_out;

    unsigned int* hT_p  = (unsigned int*)d_ws;                            // 65536*128*4 = 32 MB
    float*        part  = (float*)((char*)d_ws + ((size_t)32 << 20));     // 4 MB
    float*        res1T = (float*)((char*)d_ws + ((size_t)40 << 20));     // 128 KB

    const size_t smem1 = 65536 + 1024 + 4096;  // 70,656 B
    (void)hipFuncSetAttribute((const void*)lstm_k,
                              hipFuncAttributeMaxDynamicSharedMemorySize, (int)smem1);

    hipLaunchKernelGGL(lstm_k, dim3(B_), dim3(NTH), smem1, stream,
                       x, w_ih, w_hh, b_ih, b_hh, hT_p);
    hipLaunchKernelGGL(gemm1_k, dim3(16, 32), dim3(256), 0, stream, hT_p, w1, part);
    hipLaunchKernelGGL(reduce_k, dim3(256), dim3(128), 0, stream, part, b1, res1T);
    hipLaunchKernelGGL(head_k, dim3(B_), dim3(512), 0, stream,
                       res1T, w2, b2, w3, b3, out);
}

// Round 6
// 2776.362 us; speedup vs baseline: 1.0803x; 1.0803x over previous
//
#include <hip/hip_runtime.h>
#include <hip/hip_fp16.h>

#define B_    128
#define T_    1024
#define NTH   256
#define NVP   52   // f16 pairs per row in arch VGPRs  (pairs   0..51)
#define NAP   52   // f16 pairs per row in AGPRs       (pairs  52..103)
#define NLP   24   // f16 pairs per row in LDS         (pairs 104..127)
#define NQV   13   // h-quads for VGPR part
#define NQA   13   // h-quads for AGPR part
#define NQL   6    // h-quads for LDS part

typedef _Float16 half2_t __attribute__((ext_vector_type(2)));

__device__ __forceinline__ float fdot2(unsigned int w, unsigned int h, float acc) {
    return __builtin_amdgcn_fdot2(__builtin_bit_cast(half2_t, w),
                                  __builtin_bit_cast(half2_t, h), acc, false);
}
__device__ __forceinline__ unsigned int packf16(float a, float b) {
    half2_t h;
    h.x = (_Float16)a;
    h.y = (_Float16)b;
    return __builtin_bit_cast(unsigned int, h);
}
// Explicit AGPR residency (compiler won't use AGPRs for non-MFMA data).
#define AGPR_WRITE(dst, src) \
    asm volatile("v_accvgpr_write_b32 %0, %1" : "=a"(dst) : "v"(src))
#define AGPR_READ(dst, src) \
    asm volatile("v_accvgpr_read_b32 %0, %1" : "=v"(dst) : "a"(src))

// ---------------------------------------------------------------------------
// Kernel 1: persistent LSTM. 1 block/batch, 256 threads, 1 wave/SIMD.
// Thread u owns all 4 gate rows of unit u -> thread-local activation,
// 1 barrier/step. Weight split per row: 52 pairs arch-VGPR, 52 pairs AGPR
// (explicit accvgpr asm), 24 pairs LDS ([quad][thread], conflict-free).
// h double-buffered as packed f16 pairs in LDS.
// ---------------------------------------------------------------------------
__global__ __attribute__((amdgpu_flat_work_group_size(NTH, NTH),
                          amdgpu_waves_per_eu(1, 1)))
void lstm_k(const float* __restrict__ x, const float* __restrict__ w_ih,
            const float* __restrict__ w_hh, const float* __restrict__ b_ih,
            const float* __restrict__ b_hh, unsigned int* __restrict__ hT_p) {
    extern __shared__ unsigned char smem[];
    uint4*        w_lds4 = (uint4*)smem;                      // [24][256] quads = 96 KB
    unsigned int* hbuf   = (unsigned int*)(smem + 98304);     // [2][128] packed f16 pairs
    float*        xseq   = (float*)(smem + 98304 + 1024);     // [1024]

    const int u = threadIdx.x;
    const int b = blockIdx.x;

    float bs[4], wi[4];
#pragma unroll
    for (int g = 0; g < 4; ++g) {
        const int r = g * 256 + u;
        bs[g] = b_ih[r] + b_hh[r];
        wi[g] = w_ih[r];
    }

    // xseq[t] = x[b, (t%512)*2 + t/512]
    for (int t = u; t < T_; t += NTH)
        xseq[t] = x[b * T_ + ((t & 511) << 1) + (t >> 9)];

    // ---- weights: arch-VGPR part, pairs [0, 52) ----
    unsigned int wv[4][NVP];
#pragma unroll
    for (int g = 0; g < 4; ++g) {
        const float* row = &w_hh[(size_t)(g * 256 + u) * 256];
#pragma unroll
        for (int p = 0; p < NVP; p += 2) {
            float4 a4 = *(const float4*)&row[2 * p];
            wv[g][p]     = packf16(a4.x, a4.y);
            wv[g][p + 1] = packf16(a4.z, a4.w);
        }
    }
    // ---- weights: AGPR part, pairs [52, 104) ----
    unsigned int wa[4][NAP];
#pragma unroll
    for (int g = 0; g < 4; ++g) {
        const float* row = &w_hh[(size_t)(g * 256 + u) * 256];
#pragma unroll
        for (int p = 0; p < NAP; p += 2) {
            float4 a4 = *(const float4*)&row[2 * (NVP + p)];
            unsigned int t0 = packf16(a4.x, a4.y);
            unsigned int t1 = packf16(a4.z, a4.w);
            AGPR_WRITE(wa[g][p], t0);
            AGPR_WRITE(wa[g][p + 1], t1);
        }
    }
    // ---- weights: LDS part, pairs [104, 128) -> quad (g*6+j), lane u ----
#pragma unroll
    for (int g = 0; g < 4; ++g) {
#pragma unroll
        for (int j = 0; j < NQL; ++j) {
            const float* src = &w_hh[(size_t)(g * 256 + u) * 256 + 2 * (NVP + NAP) + 8 * j];
            float4 a4 = ((const float4*)src)[0];
            float4 c4 = ((const float4*)src)[1];
            uint4 pk;
            pk.x = packf16(a4.x, a4.y); pk.y = packf16(a4.z, a4.w);
            pk.z = packf16(c4.x, c4.y); pk.w = packf16(c4.z, c4.w);
            w_lds4[(g * NQL + j) * 256 + u] = pk;
        }
    }
    if (u < 128) { hbuf[u] = 0u; hbuf[128 + u] = 0u; }
    float c_state = 0.f;
    __syncthreads();

    for (int t = 0; t < T_; ++t) {
        const uint4* h4 = (const uint4*)&hbuf[(t & 1) * 128];
        const float  xt = xseq[t];
        float a0[4], a1[4];
#pragma unroll
        for (int g = 0; g < 4; ++g) {
            a0[g] = fmaf(xt, wi[g], bs[g]);
            a1[g] = 0.f;
        }
        // VGPR part: h quads 0..12
#pragma unroll
        for (int q = 0; q < NQV; ++q) {
            uint4 hp = h4[q];
#pragma unroll
            for (int g = 0; g < 4; ++g) {
                a0[g] = fdot2(wv[g][4 * q + 0], hp.x, a0[g]);
                a1[g] = fdot2(wv[g][4 * q + 1], hp.y, a1[g]);
                a0[g] = fdot2(wv[g][4 * q + 2], hp.z, a0[g]);
                a1[g] = fdot2(wv[g][4 * q + 3], hp.w, a1[g]);
            }
        }
        // AGPR part: h quads 13..25
#pragma unroll
        for (int q = 0; q < NQA; ++q) {
            uint4 hp = h4[NQV + q];
#pragma unroll
            for (int g = 0; g < 4; ++g) {
                unsigned int w0, w1, w2, w3;
                AGPR_READ(w0, wa[g][4 * q + 0]);
                AGPR_READ(w1, wa[g][4 * q + 1]);
                AGPR_READ(w2, wa[g][4 * q + 2]);
                AGPR_READ(w3, wa[g][4 * q + 3]);
                a0[g] = fdot2(w0, hp.x, a0[g]);
                a1[g] = fdot2(w1, hp.y, a1[g]);
                a0[g] = fdot2(w2, hp.z, a0[g]);
                a1[g] = fdot2(w3, hp.w, a1[g]);
            }
        }
        // LDS part: h quads 26..31
#pragma unroll
        for (int j = 0; j < NQL; ++j) {
            uint4 hp = h4[NQV + NQA + j];
#pragma unroll
            for (int g = 0; g < 4; ++g) {
                uint4 wq = w_lds4[(g * NQL + j) * 256 + u];
                a0[g] = fdot2(wq.x, hp.x, a0[g]);
                a1[g] = fdot2(wq.y, hp.y, a1[g]);
                a0[g] = fdot2(wq.z, hp.z, a0[g]);
                a1[g] = fdot2(wq.w, hp.w, a1[g]);
            }
        }
        const float gi = a0[0] + a1[0], gf = a0[1] + a1[1];
        const float gg = a0[2] + a1[2], go = a0[3] + a1[3];
        const float i_ = __builtin_amdgcn_rcpf(1.f + __expf(-gi));
        const float f_ = __builtin_amdgcn_rcpf(1.f + __expf(-gf));
        const float g_ = 1.f - 2.f * __builtin_amdgcn_rcpf(__expf(2.f * gg) + 1.f);
        const float o_ = __builtin_amdgcn_rcpf(1.f + __expf(-go));
        c_state = f_ * c_state + i_ * g_;
        const float h = o_ * (1.f - 2.f * __builtin_amdgcn_rcpf(__expf(2.f * c_state) + 1.f));
        ((__half*)&hbuf[((t + 1) & 1) * 128])[u] = __float2half(h);
        __syncthreads();
        if (t >= 512 && u < 128)
            hT_p[(size_t)(((t - 512) << 7) + u) * B_ + b] = hbuf[((t + 1) & 1) * 128 + u];
    }
}

// ---------------------------------------------------------------------------
// Kernel 2: res1 partials, LDS-staged. Grid (16 m-tiles, 32 k-splits),
// 256 threads. w1 packed f16 in LDS; reads wave-uniform b128 broadcasts.
// h reads coalesced. part[(ks*256+m)*128+b].
// ---------------------------------------------------------------------------
#define WST 260
__global__ __launch_bounds__(256, 2) void gemm1_k(
    const unsigned int* __restrict__ hT_p, const float* __restrict__ w1,
    float* __restrict__ part) {
    __shared__ unsigned int w_stage[16 * WST];   // 16.6 KB

    const int tid = threadIdx.x;
    const int m0  = blockIdx.x * 16;
    const int ks  = blockIdx.y;                  // 0..31
    const int bl  = tid & 127;
    const int mg  = tid >> 7;                    // wave-uniform
    const int srow = tid >> 4, slane = tid & 15;

    float acc[8];
#pragma unroll
    for (int j = 0; j < 8; ++j) acc[j] = 0.f;

    const int kbase = ks * 2048;
    for (int s = 0; s < 8; ++s) {
        const int k0 = kbase + s * 256;
        __syncthreads();
        const float* wrow = &w1[(size_t)(m0 + srow) * 131072 + 2 * k0];
#pragma unroll
        for (int i = 0; i < 8; ++i) {
            const int f = slane + 16 * i;
            float4 v = *(const float4*)&wrow[4 * f];
            w_stage[srow * WST + 2 * f]     = packf16(v.x, v.y);
            w_stage[srow * WST + 2 * f + 1] = packf16(v.z, v.w);
        }
        __syncthreads();
#pragma unroll 4
        for (int kg = 0; kg < 64; ++kg) {
            const int kp = 4 * kg;
            unsigned int h0 = hT_p[(size_t)(k0 + kp) * B_ + bl];
            unsigned int h1 = hT_p[(size_t)(k0 + kp + 1) * B_ + bl];
            unsigned int h2 = hT_p[(size_t)(k0 + kp + 2) * B_ + bl];
            unsigned int h3 = hT_p[(size_t)(k0 + kp + 3) * B_ + bl];
#pragma unroll
            for (int j = 0; j < 8; ++j) {
                uint4 w = *(const uint4*)&w_stage[(mg * 8 + j) * WST + kp];
                acc[j] = fdot2(w.x, h0, acc[j]);
                acc[j] = fdot2(w.y, h1, acc[j]);
                acc[j] = fdot2(w.z, h2, acc[j]);
                acc[j] = fdot2(w.w, h3, acc[j]);
            }
        }
    }
#pragma unroll
    for (int j = 0; j < 8; ++j)
        part[(size_t)(ks * 256 + m0 + mg * 8 + j) * B_ + bl] = acc[j];
}

// ---------------------------------------------------------------------------
// Kernel 3: reduce partials over 32 k-splits (+b1, ReLU) -> res1T[m*128+b].
// ---------------------------------------------------------------------------
__global__ __launch_bounds__(128, 8) void reduce_k(
    const float* __restrict__ part, const float* __restrict__ b1,
    float* __restrict__ res1T) {
    const int m = blockIdx.x, bl = threadIdx.x;
    float s = b1[m];
#pragma unroll 8
    for (int kc = 0; kc < 32; ++kc)
        s += part[(size_t)(kc * 256 + m) * B_ + bl];
    res1T[m * B_ + bl] = fmaxf(s, 0.f);
}

// ---------------------------------------------------------------------------
// Kernel 4: res2 = res1@w2.T+b2 ; out = res2@w3.T+b3. 1 block/batch row.
// ---------------------------------------------------------------------------
__global__ __launch_bounds__(512, 2) void head_k(
    const float* __restrict__ res1T, const float* __restrict__ w2,
    const float* __restrict__ b2, const float* __restrict__ w3,
    const float* __restrict__ b3, float* __restrict__ out) {
    __shared__ float r1s[256];
    __shared__ float r2s[512];
    const int tid = threadIdx.x;
    const int b   = blockIdx.x;

    if (tid < 256) r1s[tid] = res1T[tid * B_ + b];
    __syncthreads();
    {
        float s = b2[tid];
        const float* wr = &w2[tid * 256];
#pragma unroll 4
        for (int k = 0; k < 256; k += 4) {
            float4 w = *(const float4*)&wr[k];
            s += r1s[k] * w.x + r1s[k + 1] * w.y + r1s[k + 2] * w.z + r1s[k + 3] * w.w;
        }
        r2s[tid] = s;
    }
    __syncthreads();
    if (tid < 64) {
        float s = b3[tid];
        const float* wr = &w3[tid * 512];
#pragma unroll 4
        for (int k = 0; k < 512; k += 4) {
            float4 w = *(const float4*)&wr[k];
            s += r2s[k] * w.x + r2s[k + 1] * w.y + r2s[k + 2] * w.z + r2s[k + 3] * w.w;
        }
        out[b * 64 + tid] = s;
    }
}

extern "C" void kernel_launch(void* const* d_in, const int* in_sizes, int n_in,
                              void* d_out, int out_size, void* d_ws, size_t ws_size,
                              hipStream_t stream) {
    (void)in_sizes; (void)n_in; (void)out_size; (void)ws_size;
    const float* x    = (const float*)d_in[0];
    const float* w_ih = (const float*)d_in[1];
    const float* w_hh = (const float*)d_in[2];
    const float* b_ih = (const float*)d_in[3];
    const float* b_hh = (const float*)d_in[4];
    const float* w1   = (const float*)d_in[5];
    const float* b1   = (const float*)d_in[6];
    const float* w2   = (const float*)d_in[7];
    const float* b2   = (const float*)d_in[8];
    const float* w3   = (const float*)d_in[9];
    const float* b3   = (const float*)d_in[10];
    float* out = (float*)d_out;

    unsigned int* hT_p  = (unsigned int*)d_ws;                            // 32 MB
    float*        part  = (float*)((char*)d_ws + ((size_t)32 << 20));     // 4 MB
    float*        res1T = (float*)((char*)d_ws + ((size_t)40 << 20));     // 128 KB

    const size_t smem1 = 98304 + 1024 + 4096;  // 103,424 B
    (void)hipFuncSetAttribute((const void*)lstm_k,
                              hipFuncAttributeMaxDynamicSharedMemorySize, (int)smem1);

    hipLaunchKernelGGL(lstm_k, dim3(B_), dim3(NTH), smem1, stream,
                       x, w_ih, w_hh, b_ih, b_hh, hT_p);
    hipLaunchKernelGGL(gemm1_k, dim3(16, 32), dim3(256), 0, stream, hT_p, w1, part);
    hipLaunchKernelGGL(reduce_k, dim3(256), dim3(128), 0, stream, part, b1, res1T);
    hipLaunchKernelGGL(head_k, dim3(B_), dim3(512), 0, stream,
                       res1T, w2, b2, w3, b3, out);
}

// Round 7
// 2567.850 us; speedup vs baseline: 1.1681x; 1.0812x over previous
//
#include <hip/hip_runtime.h>
#include <hip/hip_fp16.h>

#define B_    128
#define T_    1024
#define NTH   256
#define NVP   44   // f16 pairs per row in arch VGPRs  (pairs   0..43)
#define NAP   48   // f16 pairs per row in AGPRs       (pairs  44..91)
#define NLP   36   // f16 pairs per row in LDS         (pairs  92..127)
#define NQV   11   // h-quads for VGPR part
#define NQA   12   // h-quads for AGPR part
#define NQL   9    // h-quads (per row) for LDS part

typedef _Float16 half2_t __attribute__((ext_vector_type(2)));

__device__ __forceinline__ float fdot2(unsigned int w, unsigned int h, float acc) {
    return __builtin_amdgcn_fdot2(__builtin_bit_cast(half2_t, w),
                                  __builtin_bit_cast(half2_t, h), acc, false);
}
__device__ __forceinline__ unsigned int packf16(float a, float b) {
    half2_t h;
    h.x = (_Float16)a;
    h.y = (_Float16)b;
    return __builtin_bit_cast(unsigned int, h);
}
// Explicit AGPR residency (compiler won't use AGPRs for non-MFMA data).
#define AGPR_WRITE(dst, src) \
    asm volatile("v_accvgpr_write_b32 %0, %1" : "=a"(dst) : "v"(src))
#define AGPR_READ(dst, src) \
    asm volatile("v_accvgpr_read_b32 %0, %1" : "=v"(dst) : "a"(src))

// ---------------------------------------------------------------------------
// Kernel 1: persistent LSTM. 1 block/batch, 256 threads, 1 wave/SIMD.
// Thread u owns all 4 gate rows of unit u -> thread-local activation,
// 1 barrier/step. Weight split per row: 44 pairs arch-VGPR (176 regs,
// ~216 arch demand incl. working set -> no spill), 48 pairs AGPR (192 acc
// regs via explicit accvgpr asm), 36 pairs LDS (147 KB, [quad][thread],
// conflict-free). h double-buffered as packed f16 pairs in LDS.
// ---------------------------------------------------------------------------
__global__ __attribute__((amdgpu_flat_work_group_size(NTH, NTH),
                          amdgpu_waves_per_eu(1, 1)))
void lstm_k(const float* __restrict__ x, const float* __restrict__ w_ih,
            const float* __restrict__ w_hh, const float* __restrict__ b_ih,
            const float* __restrict__ b_hh, unsigned int* __restrict__ hT_p) {
    extern __shared__ unsigned char smem[];
    uint4*        w_lds4 = (uint4*)smem;                       // [36][256] quads = 144 KB
    unsigned int* hbuf   = (unsigned int*)(smem + 147456);     // [2][128] packed f16 pairs
    float*        xseq   = (float*)(smem + 147456 + 1024);     // [1024]

    const int u = threadIdx.x;
    const int b = blockIdx.x;

    float bs[4], wi[4];
#pragma unroll
    for (int g = 0; g < 4; ++g) {
        const int r = g * 256 + u;
        bs[g] = b_ih[r] + b_hh[r];
        wi[g] = w_ih[r];
    }

    // xseq[t] = x[b, (t%512)*2 + t/512]
    for (int t = u; t < T_; t += NTH)
        xseq[t] = x[b * T_ + ((t & 511) << 1) + (t >> 9)];

    // ---- weights: arch-VGPR part, pairs [0, NVP) ----
    unsigned int wv[4][NVP];
#pragma unroll
    for (int g = 0; g < 4; ++g) {
        const float* row = &w_hh[(size_t)(g * 256 + u) * 256];
#pragma unroll
        for (int p = 0; p < NVP; p += 2) {
            float4 a4 = *(const float4*)&row[2 * p];
            wv[g][p]     = packf16(a4.x, a4.y);
            wv[g][p + 1] = packf16(a4.z, a4.w);
        }
    }
    // ---- weights: AGPR part, pairs [NVP, NVP+NAP) ----
    unsigned int wa[4][NAP];
#pragma unroll
    for (int g = 0; g < 4; ++g) {
        const float* row = &w_hh[(size_t)(g * 256 + u) * 256];
#pragma unroll
        for (int p = 0; p < NAP; p += 2) {
            float4 a4 = *(const float4*)&row[2 * (NVP + p)];
            unsigned int t0 = packf16(a4.x, a4.y);
            unsigned int t1 = packf16(a4.z, a4.w);
            AGPR_WRITE(wa[g][p], t0);
            AGPR_WRITE(wa[g][p + 1], t1);
        }
    }
    // ---- weights: LDS part, pairs [NVP+NAP, 128) -> quad (g*NQL+j), lane u ----
#pragma unroll
    for (int g = 0; g < 4; ++g) {
#pragma unroll
        for (int j = 0; j < NQL; ++j) {
            const float* src = &w_hh[(size_t)(g * 256 + u) * 256 + 2 * (NVP + NAP) + 8 * j];
            float4 a4 = ((const float4*)src)[0];
            float4 c4 = ((const float4*)src)[1];
            uint4 pk;
            pk.x = packf16(a4.x, a4.y); pk.y = packf16(a4.z, a4.w);
            pk.z = packf16(c4.x, c4.y); pk.w = packf16(c4.z, c4.w);
            w_lds4[(g * NQL + j) * 256 + u] = pk;
        }
    }
    if (u < 128) { hbuf[u] = 0u; hbuf[128 + u] = 0u; }
    float c_state = 0.f;
    __syncthreads();

    for (int t = 0; t < T_; ++t) {
        const uint4* h4 = (const uint4*)&hbuf[(t & 1) * 128];
        const float  xt = xseq[t];
        float a0[4], a1[4];
#pragma unroll
        for (int g = 0; g < 4; ++g) {
            a0[g] = fmaf(xt, wi[g], bs[g]);
            a1[g] = 0.f;
        }
        // VGPR part: h quads [0, NQV)
#pragma unroll
        for (int q = 0; q < NQV; ++q) {
            uint4 hp = h4[q];
#pragma unroll
            for (int g = 0; g < 4; ++g) {
                a0[g] = fdot2(wv[g][4 * q + 0], hp.x, a0[g]);
                a1[g] = fdot2(wv[g][4 * q + 1], hp.y, a1[g]);
                a0[g] = fdot2(wv[g][4 * q + 2], hp.z, a0[g]);
                a1[g] = fdot2(wv[g][4 * q + 3], hp.w, a1[g]);
            }
        }
        // AGPR part: h quads [NQV, NQV+NQA) ; 1 read-temp live at a time
#pragma unroll
        for (int q = 0; q < NQA; ++q) {
            uint4 hp = h4[NQV + q];
#pragma unroll
            for (int g = 0; g < 4; ++g) {
                unsigned int w0, w1, w2, w3;
                AGPR_READ(w0, wa[g][4 * q + 0]);
                a0[g] = fdot2(w0, hp.x, a0[g]);
                AGPR_READ(w1, wa[g][4 * q + 1]);
                a1[g] = fdot2(w1, hp.y, a1[g]);
                AGPR_READ(w2, wa[g][4 * q + 2]);
                a0[g] = fdot2(w2, hp.z, a0[g]);
                AGPR_READ(w3, wa[g][4 * q + 3]);
                a1[g] = fdot2(w3, hp.w, a1[g]);
            }
        }
        // LDS part: h quads [NQV+NQA, 32)
#pragma unroll
        for (int j = 0; j < NQL; ++j) {
            uint4 hp = h4[NQV + NQA + j];
#pragma unroll
            for (int g = 0; g < 4; ++g) {
                uint4 wq = w_lds4[(g * NQL + j) * 256 + u];
                a0[g] = fdot2(wq.x, hp.x, a0[g]);
                a1[g] = fdot2(wq.y, hp.y, a1[g]);
                a0[g] = fdot2(wq.z, hp.z, a0[g]);
                a1[g] = fdot2(wq.w, hp.w, a1[g]);
            }
        }
        const float gi = a0[0] + a1[0], gf = a0[1] + a1[1];
        const float gg = a0[2] + a1[2], go = a0[3] + a1[3];
        const float i_ = __builtin_amdgcn_rcpf(1.f + __expf(-gi));
        const float f_ = __builtin_amdgcn_rcpf(1.f + __expf(-gf));
        const float g_ = 1.f - 2.f * __builtin_amdgcn_rcpf(__expf(2.f * gg) + 1.f);
        const float o_ = __builtin_amdgcn_rcpf(1.f + __expf(-go));
        c_state = f_ * c_state + i_ * g_;
        const float h = o_ * (1.f - 2.f * __builtin_amdgcn_rcpf(__expf(2.f * c_state) + 1.f));
        ((__half*)&hbuf[((t + 1) & 1) * 128])[u] = __float2half(h);
        __syncthreads();
        if (t >= 512 && u < 128)
            hT_p[(size_t)(((t - 512) << 7) + u) * B_ + b] = hbuf[((t + 1) & 1) * 128 + u];
    }
}

// ---------------------------------------------------------------------------
// Kernel 2: res1 partials, LDS-staged. Grid (16 m-tiles, 32 k-splits),
// 256 threads. w1 packed f16 in LDS; reads wave-uniform b128 broadcasts.
// h reads coalesced. part[(ks*256+m)*128+b].
// ---------------------------------------------------------------------------
#define WST 260
__global__ __launch_bounds__(256, 2) void gemm1_k(
    const unsigned int* __restrict__ hT_p, const float* __restrict__ w1,
    float* __restrict__ part) {
    __shared__ unsigned int w_stage[16 * WST];   // 16.6 KB

    const int tid = threadIdx.x;
    const int m0  = blockIdx.x * 16;
    const int ks  = blockIdx.y;                  // 0..31
    const int bl  = tid & 127;
    const int mg  = tid >> 7;                    // wave-uniform
    const int srow = tid >> 4, slane = tid & 15;

    float acc[8];
#pragma unroll
    for (int j = 0; j < 8; ++j) acc[j] = 0.f;

    const int kbase = ks * 2048;
    for (int s = 0; s < 8; ++s) {
        const int k0 = kbase + s * 256;
        __syncthreads();
        const float* wrow = &w1[(size_t)(m0 + srow) * 131072 + 2 * k0];
#pragma unroll
        for (int i = 0; i < 8; ++i) {
            const int f = slane + 16 * i;
            float4 v = *(const float4*)&wrow[4 * f];
            w_stage[srow * WST + 2 * f]     = packf16(v.x, v.y);
            w_stage[srow * WST + 2 * f + 1] = packf16(v.z, v.w);
        }
        __syncthreads();
#pragma unroll 4
        for (int kg = 0; kg < 64; ++kg) {
            const int kp = 4 * kg;
            unsigned int h0 = hT_p[(size_t)(k0 + kp) * B_ + bl];
            unsigned int h1 = hT_p[(size_t)(k0 + kp + 1) * B_ + bl];
            unsigned int h2 = hT_p[(size_t)(k0 + kp + 2) * B_ + bl];
            unsigned int h3 = hT_p[(size_t)(k0 + kp + 3) * B_ + bl];
#pragma unroll
            for (int j = 0; j < 8; ++j) {
                uint4 w = *(const uint4*)&w_stage[(mg * 8 + j) * WST + kp];
                acc[j] = fdot2(w.x, h0, acc[j]);
                acc[j] = fdot2(w.y, h1, acc[j]);
                acc[j] = fdot2(w.z, h2, acc[j]);
                acc[j] = fdot2(w.w, h3, acc[j]);
            }
        }
    }
#pragma unroll
    for (int j = 0; j < 8; ++j)
        part[(size_t)(ks * 256 + m0 + mg * 8 + j) * B_ + bl] = acc[j];
}

// ---------------------------------------------------------------------------
// Kernel 3: reduce partials over 32 k-splits (+b1, ReLU) -> res1T[m*128+b].
// ---------------------------------------------------------------------------
__global__ __launch_bounds__(128, 8) void reduce_k(
    const float* __restrict__ part, const float* __restrict__ b1,
    float* __restrict__ res1T) {
    const int m = blockIdx.x, bl = threadIdx.x;
    float s = b1[m];
#pragma unroll 8
    for (int kc = 0; kc < 32; ++kc)
        s += part[(size_t)(kc * 256 + m) * B_ + bl];
    res1T[m * B_ + bl] = fmaxf(s, 0.f);
}

// ---------------------------------------------------------------------------
// Kernel 4: res2 = res1@w2.T+b2 ; out = res2@w3.T+b3. 1 block/batch row.
// ---------------------------------------------------------------------------
__global__ __launch_bounds__(512, 2) void head_k(
    const float* __restrict__ res1T, const float* __restrict__ w2,
    const float* __restrict__ b2, const float* __restrict__ w3,
    const float* __restrict__ b3, float* __restrict__ out) {
    __shared__ float r1s[256];
    __shared__ float r2s[512];
    const int tid = threadIdx.x;
    const int b   = blockIdx.x;

    if (tid < 256) r1s[tid] = res1T[tid * B_ + b];
    __syncthreads();
    {
        float s = b2[tid];
        const float* wr = &w2[tid * 256];
#pragma unroll 4
        for (int k = 0; k < 256; k += 4) {
            float4 w = *(const float4*)&wr[k];
            s += r1s[k] * w.x + r1s[k + 1] * w.y + r1s[k + 2] * w.z + r1s[k + 3] * w.w;
        }
        r2s[tid] = s;
    }
    __syncthreads();
    if (tid < 64) {
        float s = b3[tid];
        const float* wr = &w3[tid * 512];
#pragma unroll 4
        for (int k = 0; k < 512; k += 4) {
            float4 w = *(const float4*)&wr[k];
            s += r2s[k] * w.x + r2s[k + 1] * w.y + r2s[k + 2] * w.z + r2s[k + 3] * w.w;
        }
        out[b * 64 + tid] = s;
    }
}

extern "C" void kernel_launch(void* const* d_in, const int* in_sizes, int n_in,
                              void* d_out, int out_size, void* d_ws, size_t ws_size,
                              hipStream_t stream) {
    (void)in_sizes; (void)n_in; (void)out_size; (void)ws_size;
    const float* x    = (const float*)d_in[0];
    const float* w_ih = (const float*)d_in[1];
    const float* w_hh = (const float*)d_in[2];
    const float* b_ih = (const float*)d_in[3];
    const float* b_hh = (const float*)d_in[4];
    const float* w1   = (const float*)d_in[5];
    const float* b1   = (const float*)d_in[6];
    const float* w2   = (const float*)d_in[7];
    const float* b2   = (const float*)d_in[8];
    const float* w3   = (const float*)d_in[9];
    const float* b3   = (const float*)d_in[10];
    float* out = (float*)d_out;

    unsigned int* hT_p  = (unsigned int*)d_ws;                            // 32 MB
    float*        part  = (float*)((char*)d_ws + ((size_t)32 << 20));     // 4 MB
    float*        res1T = (float*)((char*)d_ws + ((size_t)40 << 20));     // 128 KB

    const size_t smem1 = 147456 + 1024 + 4096;  // 152,576 B
    (void)hipFuncSetAttribute((const void*)lstm_k,
                              hipFuncAttributeMaxDynamicSharedMemorySize, (int)smem1);

    hipLaunchKernelGGL(lstm_k, dim3(B_), dim3(NTH), smem1, stream,
                       x, w_ih, w_hh, b_ih, b_hh, hT_p);
    hipLaunchKernelGGL(gemm1_k, dim3(16, 32), dim3(256), 0, stream, hT_p, w1, part);
    hipLaunchKernelGGL(reduce_k, dim3(256), dim3(128), 0, stream, part, b1, res1T);
    hipLaunchKernelGGL(head_k, dim3(B_), dim3(512), 0, stream,
                       res1T, w2, b2, w3, b3, out);
}